// Round 5
// baseline (3547.066 us; speedup 1.0000x reference)
//
#include <hip/hip_runtime.h>

// convEP: 10-step EP relaxation, MFMA triple-bf16-split convs (fp32-equivalent).
//   s0' = rho(fc(s1));  s1' = rho(pool(conv0(s2)) + fc^T(s0));  s2' = rho(p2 + convT(unpool(s1, idx1)))
// Convs = 25 tap-GEMMs (K=in-channels) on v_mfma_f32_16x16x32_bf16, with fp32 emulated as
// 3-way bf16 split x = xh + xm + xl (8+8+8 mantissa bits ~ fp32). Product:
//   A*B ~= Ah*Bh + (Ah*Bm + Am*Bh) + (Ah*Bl + Am*Bm + Al*Bh); neglected terms <= 2^-32.
// All 6 terms accumulate into ONE fp32 accumulator (bf16 exponent range = fp32's).
// MFMA layouts: A[m=lane&15][k=quad*8+j], B[k=quad*8+j][n=lane&15], C/D: col=lane&15, row=quad*4+reg.

typedef short bf16x8 __attribute__((ext_vector_type(8)));
typedef float f32x4 __attribute__((ext_vector_type(4)));
#define MFMA16(A, B, C) __builtin_amdgcn_mfma_f32_16x16x32_bf16((A), (B), (C), 0, 0, 0)

static __device__ __forceinline__ float rho_(float x) {
  return fminf(fmaxf(x, 0.0f), 1.0f);
}
static __device__ __forceinline__ unsigned short bf16_rne(float x) {
  union { float f; unsigned u; } v; v.f = x;
  unsigned u = v.u;
  return (unsigned short)((u + 0x7FFFu + ((u >> 16) & 1u)) >> 16);
}
static __device__ __forceinline__ float bf16_f(unsigned short h) {
  union { float f; unsigned u; } v; v.u = ((unsigned)h) << 16; return v.f;
}
// split v into 3 bf16 planes
static __device__ __forceinline__ void split3(float v, unsigned short& h, unsigned short& m, unsigned short& l) {
  h = bf16_rne(v);
  float r1 = v - bf16_f(h);
  m = bf16_rne(r1);
  float r2 = r1 - bf16_f(m);
  l = bf16_rne(r2);
}

// ---------------- K0: one-time weight split+transpose (3 planes each) ----------------
// wA0[(tap*128+co)*64+ci] = conv0w[co][ci][tap]   (conv0 A operand, k=ci contiguous)
// wA1[(tap*64+o)*128+cp]  = conv0w[cp][o][tap]    (convT A operand, k=cp contiguous)
__global__ __launch_bounds__(256) void k_wprep(
    const float* __restrict__ w0,
    unsigned short* __restrict__ wA0h, unsigned short* __restrict__ wA0m, unsigned short* __restrict__ wA0l,
    unsigned short* __restrict__ wA1h, unsigned short* __restrict__ wA1m, unsigned short* __restrict__ wA1l) {
  int i = blockIdx.x * 256 + threadIdx.x;
  if (i >= 204800) return;
  {
    int ci = i & 63, r = i >> 6;
    int co = r & 127, tap = r >> 7;
    float v = w0[(co * 64 + ci) * 25 + tap];
    unsigned short h, m, l; split3(v, h, m, l);
    wA0h[i] = h; wA0m[i] = m; wA0l[i] = l;
  }
  {
    int cp = i & 127, r = i >> 7;
    int o = r & 63, tap = r >> 6;
    float v = w0[(cp * 64 + o) * 25 + tap];
    unsigned short h, m, l; split3(v, h, m, l);
    wA1h[i] = h; wA1m[i] = m; wA1l[i] = l;
  }
}

// ---------------- K1: p2 = maxpool2x2(conv2d(data, conv1_w) + conv1_b) (once) ----------------
__global__ __launch_bounds__(256) void k_p2(
    const float* __restrict__ data, const float* __restrict__ w,
    const float* __restrict__ bias, float* __restrict__ p2) {
  __shared__ float ld[3][36][36];
  __shared__ float lw[80];
  int b = blockIdx.x, co = blockIdx.y, tid = threadIdx.x;
  for (int i = tid; i < 3 * 36 * 36; i += 256) {
    int ci = i / 1296, rem = i % 1296, y = rem / 36, x = rem % 36;
    int gy = y - 2, gx = x - 2;
    float v = 0.f;
    if (gy >= 0 && gy < 32 && gx >= 0 && gx < 32)
      v = data[(b * 3 + ci) * 1024 + gy * 32 + gx];
    ld[ci][y][x] = v;
  }
  if (tid < 75) lw[tid] = w[co * 75 + tid];
  __syncthreads();
  int ph = tid >> 4, pw = tid & 15;
  float bv = bias[co];
  float a00 = bv, a01 = bv, a10 = bv, a11 = bv;
  int ry = 2 * ph, rx = 2 * pw;
  for (int ci = 0; ci < 3; ci++) {
#pragma unroll
    for (int ky = 0; ky < 5; ky++) {
#pragma unroll
      for (int kx = 0; kx < 5; kx++) {
        float wv = lw[(ci * 5 + ky) * 5 + kx];
        a00 += wv * ld[ci][ry + ky][rx + kx];
        a01 += wv * ld[ci][ry + ky][rx + kx + 1];
        a10 += wv * ld[ci][ry + ky + 1][rx + kx];
        a11 += wv * ld[ci][ry + ky + 1][rx + kx + 1];
      }
    }
  }
  float m = fmaxf(fmaxf(a00, a01), fmaxf(a10, a11));
  p2[((b * 64 + co) * 16 + ph) * 16 + pw] = m;
}

// ---------------- K2: MFMA conv0 + pool/argmax -> p1, u ----------------
// grid (64 img, 4 quadrant), block 256 = 4 waves. Wave = one n-tile (16 positions),
// all 128 co (8 m-tiles). K = 64 ci per tap (2 MFMA k-chunks).
__global__ __launch_bounds__(256, 1) void k_conv0(
    const float* __restrict__ s2,
    const unsigned short* __restrict__ wA0h, const unsigned short* __restrict__ wA0m,
    const unsigned short* __restrict__ wA0l,
    const float* __restrict__ b0, const float* __restrict__ s1old,
    float* __restrict__ p1, float* __restrict__ u) {
  __shared__ __align__(16) unsigned short smem_us[3 * 10368];  // Th|Tm|Tl, 62208 B
  unsigned short* Th = smem_us;
  unsigned short* Tm = smem_us + 10368;
  unsigned short* Tl = smem_us + 20736;

  int b = blockIdx.x, q = blockIdx.y, tid = threadIdx.x;
  int qy = q >> 1, qx = q & 1;

  // stage s2 quadrant halo (12x12 x 64ci) as 3 bf16 planes, layout [pos][ci] stride 72
  const float* s2b = s2 + b * 64 * 256;
  for (int i = tid; i < 64 * 144; i += 256) {
    int c = i / 144, pos = i % 144;
    int ty = pos / 12, tx = pos % 12;
    int gy = 8 * qy - 2 + ty, gx = 8 * qx - 2 + tx;
    float v = 0.f;
    if (gy >= 0 && gy < 16 && gx >= 0 && gx < 16) v = s2b[c * 256 + gy * 16 + gx];
    unsigned short h, m, l; split3(v, h, m, l);
    Th[pos * 72 + c] = h;
    Tm[pos * 72 + c] = m;
    Tl[pos * 72 + c] = l;
  }
  __syncthreads();

  int lane = tid & 63, wv = tid >> 6;
  int l16 = lane & 15, quad = lane >> 4;
  int wy = (l16 >> 1) & 1, wx = l16 & 1, px = l16 >> 2;
  int y_l = wv * 2 + wy;   // 0..7 in quadrant
  int x_l = px * 2 + wx;   // 0..7

  f32x4 acc[8];
#pragma unroll
  for (int m = 0; m < 8; m++) {
    int cb = m * 16 + quad * 4;
    f32x4 a; a[0] = b0[cb]; a[1] = b0[cb + 1]; a[2] = b0[cb + 2]; a[3] = b0[cb + 3];
    acc[m] = a;
  }

  for (int tap = 0; tap < 25; tap++) {
    int ky = tap / 5, kx = tap % 5;
    int hy = y_l + ky, hx = x_l + kx;           // halo coords (origin -2)
    int boffBase = (hy * 12 + hx) * 72 + quad * 8;
    int aoffBase = tap * 8192 + l16 * 64 + quad * 8;
#pragma unroll
    for (int ks = 0; ks < 2; ks++) {
      bf16x8 Bh = *(const bf16x8*)(Th + boffBase + ks * 32);
      bf16x8 Bm = *(const bf16x8*)(Tm + boffBase + ks * 32);
      bf16x8 Bl = *(const bf16x8*)(Tl + boffBase + ks * 32);
      int aoff = aoffBase + ks * 32;
#pragma unroll
      for (int m = 0; m < 8; m++) {
        bf16x8 Ah = *(const bf16x8*)(wA0h + aoff + m * 1024);
        bf16x8 Am = *(const bf16x8*)(wA0m + aoff + m * 1024);
        bf16x8 Al = *(const bf16x8*)(wA0l + aoff + m * 1024);
        acc[m] = MFMA16(Al, Bh, acc[m]);
        acc[m] = MFMA16(Am, Bm, acc[m]);
        acc[m] = MFMA16(Ah, Bl, acc[m]);
        acc[m] = MFMA16(Am, Bh, acc[m]);
        acc[m] = MFMA16(Ah, Bm, acc[m]);
        acc[m] = MFMA16(Ah, Bh, acc[m]);
      }
    }
  }

  // C -> LDS round-trip (reuse smem), then pool/argmax/u epilogue
  __syncthreads();
  float* Cb = (float*)smem_us;   // [co 128][n 64] fp32 = 32 KB
#pragma unroll
  for (int m = 0; m < 8; m++) {
#pragma unroll
    for (int r = 0; r < 4; r++) {
      Cb[(m * 16 + quad * 4 + r) * 64 + wv * 16 + l16] = acc[m][r];
    }
  }
  __syncthreads();
  for (int t2 = tid; t2 < 2048; t2 += 256) {
    int win = t2 & 15, co = t2 >> 4;   // win = py*4+px
    int base = co * 64 + win * 4;
    float v0 = Cb[base], v1 = Cb[base + 1], v2 = Cb[base + 2], v3 = Cb[base + 3];
    float m0 = v0; int id = 0;
    if (v1 > m0) { m0 = v1; id = 1; }
    if (v2 > m0) { m0 = v2; id = 2; }
    if (v3 > m0) { m0 = v3; id = 3; }
    int py = win >> 2, pxw = win & 3;
    int ph = qy * 4 + py, pw = qx * 4 + pxw;
    int pidx = ((b * 128 + co) * 8 + ph) * 8 + pw;
    p1[pidx] = m0;
    float sv = s1old[pidx];
    float* ub = u + ((b * 128 + co) * 16 + 2 * ph) * 16 + 2 * pw;
    ub[0]  = (id == 0) ? sv : 0.f;
    ub[1]  = (id == 1) ? sv : 0.f;
    ub[16] = (id == 2) ? sv : 0.f;
    ub[17] = (id == 3) ? sv : 0.f;
  }
}

// ---------------- K3: MFMA convT -> s2_new = rho(p2 + up) ----------------
// up[o,y,x] = sum_{cp,ky,kx} W0[cp][o][ky][kx] * u[cp, y+2-ky, x+2-kx]
// grid (64 img, 4 quadrant), block 256 = 4 waves (wave = n-tile), 4 m-tiles (o=64).
// K = 128 cp per tap, staged in 2 chunks of 64.
__global__ __launch_bounds__(256, 1) void k_convT(
    const float* __restrict__ u,
    const unsigned short* __restrict__ wA1h, const unsigned short* __restrict__ wA1m,
    const unsigned short* __restrict__ wA1l,
    const float* __restrict__ p2, float* __restrict__ s2new) {
  __shared__ __align__(16) unsigned short smem_us[3 * 10368];
  unsigned short* Th = smem_us;
  unsigned short* Tm = smem_us + 10368;
  unsigned short* Tl = smem_us + 20736;

  int b = blockIdx.x, q = blockIdx.y, tid = threadIdx.x;
  int qy = q >> 1, qx = q & 1;

  int lane = tid & 63, wv = tid >> 6;
  int l16 = lane & 15, quad = lane >> 4;
  int wy = (l16 >> 1) & 1, wx = l16 & 1, px = l16 >> 2;
  int y_l = wv * 2 + wy, x_l = px * 2 + wx;

  f32x4 acc[4];
#pragma unroll
  for (int m = 0; m < 4; m++) { f32x4 z; z[0] = 0.f; z[1] = 0.f; z[2] = 0.f; z[3] = 0.f; acc[m] = z; }

  for (int ch = 0; ch < 2; ch++) {
    __syncthreads();   // protect planes from previous chunk's readers
    const float* ub = u + (b * 128 + ch * 64) * 256;
    for (int i = tid; i < 64 * 144; i += 256) {
      int c = i / 144, pos = i % 144;
      int ty = pos / 12, tx = pos % 12;
      int gy = 8 * qy - 2 + ty, gx = 8 * qx - 2 + tx;
      float v = 0.f;
      if (gy >= 0 && gy < 16 && gx >= 0 && gx < 16) v = ub[c * 256 + gy * 16 + gx];
      unsigned short h, m, l; split3(v, h, m, l);
      Th[pos * 72 + c] = h;
      Tm[pos * 72 + c] = m;
      Tl[pos * 72 + c] = l;
    }
    __syncthreads();

    for (int tap = 0; tap < 25; tap++) {
      int ky = tap / 5, kx = tap % 5;
      int hy = y_l + 4 - ky, hx = x_l + 4 - kx;   // input row y+2-ky -> halo +2
      int boffBase = (hy * 12 + hx) * 72 + quad * 8;
      int aoffBase = tap * 8192 + l16 * 128 + ch * 64 + quad * 8;
#pragma unroll
      for (int ks = 0; ks < 2; ks++) {
        bf16x8 Bh = *(const bf16x8*)(Th + boffBase + ks * 32);
        bf16x8 Bm = *(const bf16x8*)(Tm + boffBase + ks * 32);
        bf16x8 Bl = *(const bf16x8*)(Tl + boffBase + ks * 32);
        int aoff = aoffBase + ks * 32;
#pragma unroll
        for (int m = 0; m < 4; m++) {
          bf16x8 Ah = *(const bf16x8*)(wA1h + aoff + m * 2048);
          bf16x8 Am = *(const bf16x8*)(wA1m + aoff + m * 2048);
          bf16x8 Al = *(const bf16x8*)(wA1l + aoff + m * 2048);
          acc[m] = MFMA16(Al, Bh, acc[m]);
          acc[m] = MFMA16(Am, Bm, acc[m]);
          acc[m] = MFMA16(Ah, Bl, acc[m]);
          acc[m] = MFMA16(Am, Bh, acc[m]);
          acc[m] = MFMA16(Ah, Bm, acc[m]);
          acc[m] = MFMA16(Ah, Bh, acc[m]);
        }
      }
    }
  }

  // direct epilogue: lane = one position (y,x), rows = o
  int y = qy * 8 + y_l, x = qx * 8 + x_l;
#pragma unroll
  for (int m = 0; m < 4; m++) {
#pragma unroll
    for (int r = 0; r < 4; r++) {
      int o = m * 16 + quad * 4 + r;
      int idx = ((b * 64 + o) * 16 + y) * 16 + x;
      s2new[idx] = rho_(p2[idx] + acc[m][r]);
    }
  }
}

// ---------------- K4: s1_new = rho(p1 + reshape(s0_old @ fc_w)) ----------------
__global__ __launch_bounds__(256) void k_s1fc(
    const float* __restrict__ p1, const float* __restrict__ s0old,
    const float* __restrict__ fcw, float* __restrict__ s1new) {
  int i = blockIdx.x * 256 + threadIdx.x;
  int b = i >> 13, j = i & 8191;
  float a = p1[i];
#pragma unroll
  for (int k = 0; k < 10; k++) a += s0old[b * 10 + k] * fcw[k * 8192 + j];
  s1new[i] = rho_(a);
}

// ---------------- K5: s0_new = rho(s1_old_flat @ fc_w^T + fc_b) ----------------
__global__ __launch_bounds__(256) void k_s0fc(
    const float* __restrict__ s1old, const float* __restrict__ fcw,
    const float* __restrict__ fcb, float* __restrict__ s0new) {
  __shared__ float red[10][256];
  int b = blockIdx.x, tid = threadIdx.x;
  float acc[10];
#pragma unroll
  for (int o = 0; o < 10; o++) acc[o] = 0.f;
  const float* sb = s1old + b * 8192;
  for (int i = tid; i < 8192; i += 256) {
    float v = sb[i];
#pragma unroll
    for (int o = 0; o < 10; o++) acc[o] += v * fcw[o * 8192 + i];
  }
#pragma unroll
  for (int o = 0; o < 10; o++) red[o][tid] = acc[o];
  __syncthreads();
  for (int s = 128; s > 0; s >>= 1) {
    if (tid < s) {
#pragma unroll
      for (int o = 0; o < 10; o++) red[o][tid] += red[o][tid + s];
    }
    __syncthreads();
  }
  if (tid < 10) s0new[b * 10 + tid] = rho_(red[tid][0] + fcb[tid]);
}

extern "C" void kernel_launch(void* const* d_in, const int* in_sizes, int n_in,
                              void* d_out, int out_size, void* d_ws, size_t ws_size,
                              hipStream_t stream) {
  const float* data   = (const float*)d_in[0];
  const float* s0init = (const float*)d_in[1];   // zeros
  const float* s1init = (const float*)d_in[2];   // zeros
  const float* s2init = (const float*)d_in[3];   // zeros
  const float* conv0w = (const float*)d_in[4];
  const float* conv0b = (const float*)d_in[5];
  const float* conv1w = (const float*)d_in[6];
  const float* conv1b = (const float*)d_in[7];
  const float* fcw    = (const float*)d_in[8];
  const float* fcb    = (const float*)d_in[9];

  // workspace layout: floats then bf16 weight planes (~29.7 MB total)
  float* p = (float*)d_ws;
  float* s0buf[2] = {p, p + 640};            p += 1280;
  float* s1buf[2] = {p, p + 524288};         p += 1048576;
  float* s2buf[2] = {p, p + 1048576};        p += 2097152;
  float* p1 = p;                             p += 524288;
  float* p2 = p;                             p += 1048576;
  float* u  = p;                             p += 2097152;
  unsigned short* wq = (unsigned short*)p;
  unsigned short* wA0h = wq;                 wq += 204800;
  unsigned short* wA0m = wq;                 wq += 204800;
  unsigned short* wA0l = wq;                 wq += 204800;
  unsigned short* wA1h = wq;                 wq += 204800;
  unsigned short* wA1m = wq;                 wq += 204800;
  unsigned short* wA1l = wq;                 wq += 204800;

  // one-time: weight split/transpose + loop-invariant p2
  k_wprep<<<800, 256, 0, stream>>>(conv0w, wA0h, wA0m, wA0l, wA1h, wA1m, wA1l);
  k_p2<<<dim3(64, 64), 256, 0, stream>>>(data, conv1w, conv1b, p2);

  const float* s0o = s0init;
  const float* s1o = s1init;
  const float* s2o = s2init;
  float* outp = (float*)d_out;

  for (int t = 0; t < 10; t++) {
    int nb = t & 1;
    float* s0w = s0buf[nb];
    float* s1w = s1buf[nb];
    float* s2w = s2buf[nb];

    k_conv0<<<dim3(64, 4), 256, 0, stream>>>(s2o, wA0h, wA0m, wA0l, conv0b, s1o, p1, u);
    k_s0fc<<<64, 256, 0, stream>>>(s1o, fcw, fcb, s0w);
    k_s1fc<<<2048, 256, 0, stream>>>(p1, s0o, fcw, s1w);
    k_convT<<<dim3(64, 4), 256, 0, stream>>>(u, wA1h, wA1m, wA1l, p2, s2w);

    s0o = s0w; s1o = s1w; s2o = s2w;

    if (t == 6) {   // PRED_T snapshot (post-update states)
      hipMemcpyAsync(outp + 1573504, s0w, 640 * sizeof(float),     hipMemcpyDeviceToDevice, stream);
      hipMemcpyAsync(outp + 1574144, s1w, 524288 * sizeof(float),  hipMemcpyDeviceToDevice, stream);
      hipMemcpyAsync(outp + 2098432, s2w, 1048576 * sizeof(float), hipMemcpyDeviceToDevice, stream);
    }
  }

  // final states
  hipMemcpyAsync(outp + 0,      s0o, 640 * sizeof(float),     hipMemcpyDeviceToDevice, stream);
  hipMemcpyAsync(outp + 640,    s1o, 524288 * sizeof(float),  hipMemcpyDeviceToDevice, stream);
  hipMemcpyAsync(outp + 524928, s2o, 1048576 * sizeof(float), hipMemcpyDeviceToDevice, stream);
}

// Round 6
// 1426.232 us; speedup vs baseline: 2.4870x; 2.4870x over previous
//
#include <hip/hip_runtime.h>

// convEP: 10-step EP relaxation, MFMA fp16 2-way-split convs (fp32-equivalent).
//   s0' = rho(fc(s1));  s1' = rho(pool(conv0(s2)) + fc^T(s0));  s2' = rho(p2 + convT(unpool(s1, idx1)))
// fp32 x = xh + 2^-12*xl' (xh,xl' fp16, lo pre-scaled 2^12 to dodge subnormal flush).
// x*y ~= xh*yh  +  2^-12*(xh*yl' + xl'*yh)   [dropped xl*yl ~ 2^-24]
// acc_hi accumulates hh terms, acc_lo the scaled cross terms; combine at epilogue.
// MFMA 16x16x32_f16 layouts: A[m=l16][k=quad*8+j], B[k=quad*8+j][n=l16], C/D: col=l16, row=quad*4+reg.

typedef _Float16 half8 __attribute__((ext_vector_type(8)));
typedef float f32x4 __attribute__((ext_vector_type(4)));
#define MFMA_F16(A, B, C) __builtin_amdgcn_mfma_f32_16x16x32_f16((A), (B), (C), 0, 0, 0)

static __device__ __forceinline__ float rho_(float x) {
  return fminf(fmaxf(x, 0.0f), 1.0f);
}
// split v = h + lo/4096 (lo prescaled so both planes stay fp16-normal)
static __device__ __forceinline__ void split2(float v, _Float16& h, _Float16& l) {
  if (fabsf(v) < 6.1035156e-5f) {
    h = (_Float16)0.f;
    l = (_Float16)(v * 4096.f);
  } else {
    h = (_Float16)v;
    l = (_Float16)((v - (float)h) * 4096.f);
  }
}

// ---------------- K0: one-time weight split+transpose (fp16 hi/lo-scaled planes) ----------------
// wA0[((tap*2+ck)*128 + co)*32 + cik] = conv0w[co][ck*32+cik][tap]   (conv0 A: m=co, k=ci)
// wA1[((tap*4+c )*64  + o )*32 + cpk] = conv0w[c*32+cpk][o][tap]    (convT A: m=o,  k=cp)
__global__ __launch_bounds__(256) void k_wprep(
    const float* __restrict__ w0,
    _Float16* __restrict__ wA0h, _Float16* __restrict__ wA0l,
    _Float16* __restrict__ wA1h, _Float16* __restrict__ wA1l) {
  int i = blockIdx.x * 256 + threadIdx.x;
  if (i >= 204800) return;
  {
    int cik = i & 31, t1 = i >> 5;
    int co = t1 & 127, t2 = t1 >> 7;
    int ck = t2 & 1, tap = t2 >> 1;
    float v = w0[(co * 64 + ck * 32 + cik) * 25 + tap];
    _Float16 h, l; split2(v, h, l);
    wA0h[i] = h; wA0l[i] = l;
  }
  {
    int cpk = i & 31, t1 = i >> 5;
    int o = t1 & 63, t2 = t1 >> 6;
    int c = t2 & 3, tap = t2 >> 2;
    float v = w0[((c * 32 + cpk) * 64 + o) * 25 + tap];
    _Float16 h, l; split2(v, h, l);
    wA1h[i] = h; wA1l[i] = l;
  }
}

// ---------------- K1: p2 = maxpool2x2(conv2d(data, conv1_w) + conv1_b) (once, fp32) ----------------
__global__ __launch_bounds__(256) void k_p2(
    const float* __restrict__ data, const float* __restrict__ w,
    const float* __restrict__ bias, float* __restrict__ p2) {
  __shared__ float ld[3][36][36];
  __shared__ float lw[80];
  int b = blockIdx.x, co = blockIdx.y, tid = threadIdx.x;
  for (int i = tid; i < 3 * 36 * 36; i += 256) {
    int ci = i / 1296, rem = i % 1296, y = rem / 36, x = rem % 36;
    int gy = y - 2, gx = x - 2;
    float v = 0.f;
    if (gy >= 0 && gy < 32 && gx >= 0 && gx < 32)
      v = data[(b * 3 + ci) * 1024 + gy * 32 + gx];
    ld[ci][y][x] = v;
  }
  if (tid < 75) lw[tid] = w[co * 75 + tid];
  __syncthreads();
  int ph = tid >> 4, pw = tid & 15;
  float bv = bias[co];
  float a00 = bv, a01 = bv, a10 = bv, a11 = bv;
  int ry = 2 * ph, rx = 2 * pw;
  for (int ci = 0; ci < 3; ci++) {
#pragma unroll
    for (int ky = 0; ky < 5; ky++) {
#pragma unroll
      for (int kx = 0; kx < 5; kx++) {
        float wv = lw[(ci * 5 + ky) * 5 + kx];
        a00 += wv * ld[ci][ry + ky][rx + kx];
        a01 += wv * ld[ci][ry + ky][rx + kx + 1];
        a10 += wv * ld[ci][ry + ky + 1][rx + kx];
        a11 += wv * ld[ci][ry + ky + 1][rx + kx + 1];
      }
    }
  }
  float m = fmaxf(fmaxf(a00, a01), fmaxf(a10, a11));
  p2[((b * 64 + co) * 16 + ph) * 16 + pw] = m;
}

// ---------------- K2: MFMA conv0 + pool/argmax + fused s1 update; writes s1_new, u ----------------
// grid (64 img, 4 quad), 256 thr = 4 waves (mh x nh). Wave: m=4 tiles (64 co), n=2 tiles
// (4 rows of quadrant), ci = 64 in 2 k-chunks of 32. u written in [b][pos 256][cp 128] fp32.
__global__ __launch_bounds__(256, 1) void k_conv0(
    const float* __restrict__ s2,
    const _Float16* __restrict__ wA0h, const _Float16* __restrict__ wA0l,
    const float* __restrict__ b0, const float* __restrict__ s1old,
    const float* __restrict__ s0old, const float* __restrict__ fcw,
    float* __restrict__ s1new, float* __restrict__ u) {
  __shared__ __align__(16) _Float16 sm[23040];  // [ck 2][plane 2] x 144 pos x 40 (46080 B)
  int b = blockIdx.x, q = blockIdx.y, tid = threadIdx.x;
  int qy = q >> 1, qx = q & 1;

  const float* s2b = s2 + b * 16384;
  for (int i = tid; i < 9216; i += 256) {
    int ci = i / 144, pos = i % 144;
    int ty = pos / 12, tx = pos % 12;
    int gy = qy * 8 - 2 + ty, gx = qx * 8 - 2 + tx;
    float v = 0.f;
    if (gy >= 0 && gy < 16 && gx >= 0 && gx < 16) v = s2b[ci * 256 + gy * 16 + gx];
    _Float16 h, l; split2(v, h, l);
    int ck = ci >> 5, cik = ci & 31;
    sm[(ck * 2 + 0) * 5760 + pos * 40 + cik] = h;
    sm[(ck * 2 + 1) * 5760 + pos * 40 + cik] = l;
  }
  __syncthreads();

  int lane = tid & 63, w = tid >> 6;
  int mh = w & 1, nh = w >> 1;
  int l16 = lane & 15, quad = lane >> 4;
  int wy = (l16 >> 1) & 1, wx = l16 & 1, px = l16 >> 2;
  int x_l = px * 2 + wx;

  f32x4 acch[2][4], accl[2][4];
#pragma unroll
  for (int mt = 0; mt < 4; mt++) {
    int cb = mh * 64 + mt * 16 + quad * 4;
    f32x4 bi; bi[0] = b0[cb]; bi[1] = b0[cb + 1]; bi[2] = b0[cb + 2]; bi[3] = b0[cb + 3];
    f32x4 z; z[0] = 0.f; z[1] = 0.f; z[2] = 0.f; z[3] = 0.f;
    acch[0][mt] = bi; acch[1][mt] = bi;
    accl[0][mt] = z;  accl[1][mt] = z;
  }

  for (int ck = 0; ck < 2; ck++) {
    const _Float16* Tb = sm + (ck * 2) * 5760;
    for (int tap = 0; tap < 25; tap++) {
      int ky = tap / 5, kx = tap % 5;
      const _Float16* ap  = wA0h + ((tap * 2 + ck) * 128 + mh * 64 + l16) * 32 + quad * 8;
      const _Float16* alp = wA0l + ((tap * 2 + ck) * 128 + mh * 64 + l16) * 32 + quad * 8;
      half8 ah[4], al[4];
#pragma unroll
      for (int mt = 0; mt < 4; mt++) {
        ah[mt] = *(const half8*)(ap + mt * 512);
        al[mt] = *(const half8*)(alp + mt * 512);
      }
#pragma unroll
      for (int nt2 = 0; nt2 < 2; nt2++) {
        int pos = (4 * nh + 2 * nt2 + wy + ky) * 12 + (x_l + kx);
        half8 bh = *(const half8*)(Tb + pos * 40 + quad * 8);
        half8 bl = *(const half8*)(Tb + 5760 + pos * 40 + quad * 8);
#pragma unroll
        for (int mt = 0; mt < 4; mt++) {
          acch[nt2][mt] = MFMA_F16(ah[mt], bh, acch[nt2][mt]);
          accl[nt2][mt] = MFMA_F16(al[mt], bh, accl[nt2][mt]);
          accl[nt2][mt] = MFMA_F16(ah[mt], bl, accl[nt2][mt]);
        }
      }
    }
  }

  // C -> LDS (reuse), stride 66 to spread banks
  __syncthreads();
  float* Cb = (float*)sm;   // [co 128][66], 33792 B
#pragma unroll
  for (int nt2 = 0; nt2 < 2; nt2++) {
    int p64 = (4 * nh + 2 * nt2 + wy) * 8 + x_l;
#pragma unroll
    for (int mt = 0; mt < 4; mt++) {
#pragma unroll
      for (int r = 0; r < 4; r++) {
        Cb[(mh * 64 + mt * 16 + quad * 4 + r) * 66 + p64] =
            acch[nt2][mt][r] + 2.44140625e-4f * accl[nt2][mt][r];
      }
    }
  }
  __syncthreads();

  // pool/argmax + fused s1 update + u scatter
  for (int it = 0; it < 8; it++) {
    int idx = it * 256 + tid;
    int co = idx >> 4, win = idx & 15;
    int wy2 = win >> 2, wx2 = win & 3;
    int base = co * 66 + wy2 * 16 + wx2 * 2;
    float v0 = Cb[base], v1 = Cb[base + 1], v2 = Cb[base + 8], v3 = Cb[base + 9];
    float m0 = v0; int id = 0;
    if (v1 > m0) { m0 = v1; id = 1; }
    if (v2 > m0) { m0 = v2; id = 2; }
    if (v3 > m0) { m0 = v3; id = 3; }
    int ph = qy * 4 + wy2, pw = qx * 4 + wx2;
    int j = co * 64 + ph * 8 + pw;
    float a = m0;
#pragma unroll
    for (int k = 0; k < 10; k++) a += s0old[b * 10 + k] * fcw[k * 8192 + j];
    s1new[b * 8192 + j] = rho_(a);
    float sv = s1old[b * 8192 + j];
    int gp = (qy * 8 + wy2 * 2) * 16 + (qx * 8 + wx2 * 2);
    float* up = u + (b * 256 + gp) * 128 + co;
    up[0]    = (id == 0) ? sv : 0.f;
    up[128]  = (id == 1) ? sv : 0.f;
    up[2048] = (id == 2) ? sv : 0.f;
    up[2176] = (id == 3) ? sv : 0.f;
  }
}

// ---------------- K3: MFMA convT -> s2_new = rho(p2 + up) ----------------
// up[o,y,x] = sum_{cp,ky,kx} W0[cp][o][ky][kx] * u[cp, y+2-ky, x+2-kx]
// grid (64 img, 4 quad), 4 waves = cp-chunks (32 each, partials). 2 phases (hi/lo plane of u).
// Wave: n=4 tiles (whole quadrant), m=4 tiles (64 o). LDS tree-reduce, wave 0 epilogue.
__global__ __launch_bounds__(256, 1) void k_convT(
    const float* __restrict__ u, const _Float16* __restrict__ wA1h,
    const _Float16* __restrict__ wA1l, const float* __restrict__ p2,
    float* __restrict__ s2new) {
  __shared__ __align__(16) _Float16 sm[19584];   // 144 pos x 136 (39168 B); reused for reduce
  int b = blockIdx.x, q = blockIdx.y, tid = threadIdx.x;
  int qy = q >> 1, qx = q & 1;
  int lane = tid & 63, w = tid >> 6;   // w = cp-chunk
  int l16 = lane & 15, quad = lane >> 4;
  int wy = (l16 >> 1) & 1, wx = l16 & 1, px = l16 >> 2;
  int x_l = px * 2 + wx;

  f32x4 acch[4][4], accl[4][4];
#pragma unroll
  for (int nt = 0; nt < 4; nt++)
#pragma unroll
    for (int mt = 0; mt < 4; mt++) {
      f32x4 z; z[0] = 0.f; z[1] = 0.f; z[2] = 0.f; z[3] = 0.f;
      acch[nt][mt] = z; accl[nt][mt] = z;
    }

  const float* ub = u + b * 32768;
  for (int phase = 0; phase < 2; phase++) {
    __syncthreads();
    for (int i = tid; i < 18432; i += 256) {
      int cp = i & 127, pos = i >> 7;
      int ty = pos / 12, tx = pos % 12;
      int gy = qy * 8 - 2 + ty, gx = qx * 8 - 2 + tx;
      float v = 0.f;
      if (gy >= 0 && gy < 16 && gx >= 0 && gx < 16) v = ub[(gy * 16 + gx) * 128 + cp];
      _Float16 h, l; split2(v, h, l);
      sm[pos * 136 + cp] = (phase == 0) ? h : l;
    }
    __syncthreads();

    for (int tap = 0; tap < 25; tap++) {
      int ky = tap / 5, kx = tap % 5;
      const _Float16* ap = wA1h + ((tap * 4 + w) * 64 + l16) * 32 + quad * 8;
      half8 ah[4], al[4];
#pragma unroll
      for (int mt = 0; mt < 4; mt++) ah[mt] = *(const half8*)(ap + mt * 512);
      if (phase == 0) {
        const _Float16* alp = wA1l + ((tap * 4 + w) * 64 + l16) * 32 + quad * 8;
#pragma unroll
        for (int mt = 0; mt < 4; mt++) al[mt] = *(const half8*)(alp + mt * 512);
      }
#pragma unroll
      for (int nt = 0; nt < 4; nt++) {
        int pos = (2 * nt + wy + 4 - ky) * 12 + (x_l + 4 - kx);
        half8 bv = *(const half8*)(sm + pos * 136 + w * 32 + quad * 8);
#pragma unroll
        for (int mt = 0; mt < 4; mt++) {
          if (phase == 0) {
            acch[nt][mt] = MFMA_F16(ah[mt], bv, acch[nt][mt]);
            accl[nt][mt] = MFMA_F16(al[mt], bv, accl[nt][mt]);
          } else {
            accl[nt][mt] = MFMA_F16(ah[mt], bv, accl[nt][mt]);
          }
        }
      }
    }
  }

  // combine planes into acch
#pragma unroll
  for (int nt = 0; nt < 4; nt++)
#pragma unroll
    for (int mt = 0; mt < 4; mt++)
#pragma unroll
      for (int r = 0; r < 4; r++)
        acch[nt][mt][r] += 2.44140625e-4f * accl[nt][mt][r];

  // cross-wave tree reduction via LDS (regions: 2 x 4352 floats = 34816 B, fits)
  float* R = (float*)sm;
  __syncthreads();
  if (w >= 2) {
#pragma unroll
    for (int nt = 0; nt < 4; nt++)
#pragma unroll
      for (int mt = 0; mt < 4; mt++)
#pragma unroll
        for (int r = 0; r < 4; r++)
          R[(w - 2) * 4352 + lane * 68 + (nt * 4 + mt) * 4 + r] = acch[nt][mt][r];
  }
  __syncthreads();
  if (w < 2) {
#pragma unroll
    for (int nt = 0; nt < 4; nt++)
#pragma unroll
      for (int mt = 0; mt < 4; mt++)
#pragma unroll
        for (int r = 0; r < 4; r++)
          acch[nt][mt][r] += R[w * 4352 + lane * 68 + (nt * 4 + mt) * 4 + r];
  }
  __syncthreads();
  if (w == 1) {
#pragma unroll
    for (int nt = 0; nt < 4; nt++)
#pragma unroll
      for (int mt = 0; mt < 4; mt++)
#pragma unroll
        for (int r = 0; r < 4; r++)
          R[lane * 68 + (nt * 4 + mt) * 4 + r] = acch[nt][mt][r];
  }
  __syncthreads();
  if (w == 0) {
#pragma unroll
    for (int nt = 0; nt < 4; nt++) {
      int y = qy * 8 + 2 * nt + wy;
#pragma unroll
      for (int mt = 0; mt < 4; mt++) {
#pragma unroll
        for (int r = 0; r < 4; r++) {
          float v = acch[nt][mt][r] + R[lane * 68 + (nt * 4 + mt) * 4 + r];
          int o = mt * 16 + quad * 4 + r;
          int idx = ((b * 64 + o) * 16 + y) * 16 + (qx * 8 + x_l);
          s2new[idx] = rho_(p2[idx] + v);
        }
      }
    }
  }
}

// ---------------- K5: s0_new = rho(s1_old_flat @ fc_w^T + fc_b) ----------------
__global__ __launch_bounds__(256) void k_s0fc(
    const float* __restrict__ s1old, const float* __restrict__ fcw,
    const float* __restrict__ fcb, float* __restrict__ s0new) {
  __shared__ float red[10][256];
  int b = blockIdx.x, tid = threadIdx.x;
  float acc[10];
#pragma unroll
  for (int o = 0; o < 10; o++) acc[o] = 0.f;
  const float* sb = s1old + b * 8192;
  for (int i = tid; i < 8192; i += 256) {
    float v = sb[i];
#pragma unroll
    for (int o = 0; o < 10; o++) acc[o] += v * fcw[o * 8192 + i];
  }
#pragma unroll
  for (int o = 0; o < 10; o++) red[o][tid] = acc[o];
  __syncthreads();
  for (int s = 128; s > 0; s >>= 1) {
    if (tid < s) {
#pragma unroll
      for (int o = 0; o < 10; o++) red[o][tid] += red[o][tid + s];
    }
    __syncthreads();
  }
  if (tid < 10) s0new[b * 10 + tid] = rho_(red[tid][0] + fcb[tid]);
}

extern "C" void kernel_launch(void* const* d_in, const int* in_sizes, int n_in,
                              void* d_out, int out_size, void* d_ws, size_t ws_size,
                              hipStream_t stream) {
  const float* data   = (const float*)d_in[0];
  const float* s0init = (const float*)d_in[1];   // zeros
  const float* s1init = (const float*)d_in[2];   // zeros
  const float* s2init = (const float*)d_in[3];   // zeros
  const float* conv0w = (const float*)d_in[4];
  const float* conv0b = (const float*)d_in[5];
  const float* conv1w = (const float*)d_in[6];
  const float* conv1b = (const float*)d_in[7];
  const float* fcw    = (const float*)d_in[8];
  const float* fcb    = (const float*)d_in[9];

  // workspace layout (~26.8 MB)
  float* p = (float*)d_ws;
  float* s0buf[2] = {p, p + 640};            p += 1280;
  float* s1buf[2] = {p, p + 524288};         p += 1048576;
  float* s2buf[2] = {p, p + 1048576};        p += 2097152;
  float* u  = p;                             p += 2097152;   // [b][pos 256][cp 128] fp32
  float* p2 = p;                             p += 1048576;
  _Float16* wq = (_Float16*)p;
  _Float16* wA0h = wq;                       wq += 204800;
  _Float16* wA0l = wq;                       wq += 204800;
  _Float16* wA1h = wq;                       wq += 204800;
  _Float16* wA1l = wq;                       wq += 204800;

  k_wprep<<<800, 256, 0, stream>>>(conv0w, wA0h, wA0l, wA1h, wA1l);
  k_p2<<<dim3(64, 64), 256, 0, stream>>>(data, conv1w, conv1b, p2);

  const float* s0o = s0init;
  const float* s1o = s1init;
  const float* s2o = s2init;
  float* outp = (float*)d_out;

  for (int t = 0; t < 10; t++) {
    int nb = t & 1;
    float* s0w = s0buf[nb];
    float* s1w = s1buf[nb];
    float* s2w = s2buf[nb];

    // conv0(s2_old) + pool/argmax + s1_new = rho(p1 + fc^T(s0_old)); u = unpool(s1_old, idx)
    k_conv0<<<dim3(64, 4), 256, 0, stream>>>(s2o, wA0h, wA0l, conv0b, s1o, s0o, fcw, s1w, u);
    // s0_new = rho(fc(s1_old))
    k_s0fc<<<64, 256, 0, stream>>>(s1o, fcw, fcb, s0w);
    // s2_new = rho(p2 + convT(u))
    k_convT<<<dim3(64, 4), 256, 0, stream>>>(u, wA1h, wA1l, p2, s2w);

    s0o = s0w; s1o = s1w; s2o = s2w;

    if (t == 6) {   // PRED_T snapshot (post-update states)
      hipMemcpyAsync(outp + 1573504, s0w, 640 * sizeof(float),     hipMemcpyDeviceToDevice, stream);
      hipMemcpyAsync(outp + 1574144, s1w, 524288 * sizeof(float),  hipMemcpyDeviceToDevice, stream);
      hipMemcpyAsync(outp + 2098432, s2w, 1048576 * sizeof(float), hipMemcpyDeviceToDevice, stream);
    }
  }

  // final states
  hipMemcpyAsync(outp + 0,      s0o, 640 * sizeof(float),     hipMemcpyDeviceToDevice, stream);
  hipMemcpyAsync(outp + 640,    s1o, 524288 * sizeof(float),  hipMemcpyDeviceToDevice, stream);
  hipMemcpyAsync(outp + 524928, s2o, 1048576 * sizeof(float), hipMemcpyDeviceToDevice, stream);
}